// Round 3
// baseline (831.178 us; speedup 1.0000x reference)
//
#include <hip/hip_runtime.h>
#include <math.h>

// LocalSTD: out = sqrt( G*x^2 - (G*x)^2 + 1e-6 ), G = 11x11 Gaussian (sigma=1),
// separable. x: [16,64,256,256] fp32 = 1024 images of 256x256.
//
// R6: horizontal-FIRST separable order. The incoming raw row is halo-exchanged
// once (10 shuffles: x only -- the x^2 halo is computed by squaring the
// shuffled x values locally), then convolved horizontally into two register
// rings Hx[11], Hxx[11]. The vertical 11-tap is then a pure per-lane register
// reduction (zero cross-lane traffic). This halves DS-pipe work per row-step
// vs R5 (20 ds_bpermute -> 10), which profiling showed was the busiest
// compute-side pipe (~50us of per-CU LDS occupancy), and removes the square
// recompute from the vertical pass. Cost: 2 rings = 88 VGPRs; still under the
// (256,4) 128-VGPR cap (4 waves/SIMD = 16 KB/CU of prefetch in flight > the
// 9.2 KB bandwidth-delay product, so HBM streaming is preserved).
//
// Wave = 64 lanes x 4 cols = full 256-col row; band = 32 rows/wave; 2 blocks
// per image (2048 blocks).

#define W        256
#define IMG_PIX  (W * W)
#define BANDH    32          // output rows per wave; block = 4 waves = 128 rows

// normalized 1D Gaussian sigma=1 (2D kernel = outer product, sums factorize)
#define GW0 1.4867195e-06f   // |d|=5
#define GW1 1.3383023e-04f   // |d|=4
#define GW2 4.4318485e-03f   // |d|=3
#define GW3 5.3990965e-02f   // |d|=2
#define GW4 2.4197072e-01f   // |d|=1
#define GW5 3.9894228e-01f   // center

typedef float f4 __attribute__((ext_vector_type(4)));

__device__ __forceinline__ f4 vfma(float g, f4 a, f4 c) {
    f4 gv = {g, g, g, g};
    return __builtin_elementwise_fma(gv, a, c);   // -> v_pk_fma_f32 pairs
}

__device__ __forceinline__ f4 load_row(const float* __restrict__ xi, int gr, int c) {
    if ((unsigned)gr < (unsigned)W)
        return *(const f4*)(xi + (size_t)gr * W + c);
    return (f4){0.f, 0.f, 0.f, 0.f};
}

__device__ __forceinline__ f4 shfl_up1(f4 v) {
    f4 r;
    r.x = __shfl_up(v.x, 1);
    r.y = __shfl_up(v.y, 1);
    r.z = __shfl_up(v.z, 1);
    r.w = __shfl_up(v.w, 1);
    return r;
}
__device__ __forceinline__ f4 shfl_dn1(f4 v) {
    f4 r;
    r.x = __shfl_down(v.x, 1);
    r.y = __shfl_down(v.y, 1);
    r.z = __shfl_down(v.z, 1);
    r.w = __shfl_down(v.w, 1);
    return r;
}

// Horizontal 11-tap of one RAW row for this lane's 4 cols, producing both
// streams: h1 = Hconv(x), h2 = Hconv(x^2). Halo via 10 wave shuffles on x;
// the x^2 halo is the square of the shuffled x halo (no second exchange).
// Boundary lanes (== image border) zeroed by mask-multiply; shuffled garbage
// at the wave edge is the lane's own finite value, so *0.0f is safe.
__device__ __forceinline__ void hrow(f4 v, float mu1, float mu2,
                                     float md1, float md2,
                                     f4& h1, f4& h2) {
    f4 L = shfl_up1(v);                      // lane i-1: cols c-4..c-1
    float eL = __shfl_up(v.w, 2) * mu2;      // lane i-2 col c-5
    f4 R = shfl_dn1(v);                      // lane i+1: cols c+4..c+7
    float eR = __shfl_down(v.x, 2) * md2;    // lane i+2 col c+8
    L *= mu1;
    R *= md1;
    float F[14] = { eL,  L.x, L.y, L.z, L.w,
                    v.x, v.y, v.z, v.w,
                    R.x, R.y, R.z, R.w,  eR };   // F[k] = col c-5+k
    float o1[4], o2[4];
    #pragma unroll
    for (int j = 0; j < 4; ++j) {
        float s = GW5 * F[j + 5];
        s = fmaf(GW4, F[j + 4] + F[j + 6],  s);
        s = fmaf(GW3, F[j + 3] + F[j + 7],  s);
        s = fmaf(GW2, F[j + 2] + F[j + 8],  s);
        s = fmaf(GW1, F[j + 1] + F[j + 9],  s);
        s = fmaf(GW0, F[j + 0] + F[j + 10], s);
        o1[j] = s;
    }
    #pragma unroll
    for (int k = 0; k < 14; ++k)             // square in place (x^2 stream)
        F[k] = F[k] * F[k];
    #pragma unroll
    for (int j = 0; j < 4; ++j) {
        float s = GW5 * F[j + 5];
        s = fmaf(GW4, F[j + 4] + F[j + 6],  s);
        s = fmaf(GW3, F[j + 3] + F[j + 7],  s);
        s = fmaf(GW2, F[j + 2] + F[j + 8],  s);
        s = fmaf(GW1, F[j + 1] + F[j + 9],  s);
        s = fmaf(GW0, F[j + 0] + F[j + 10], s);
        o2[j] = s;
    }
    h1 = (f4){o1[0], o1[1], o1[2], o1[3]};
    h2 = (f4){o2[0], o2[1], o2[2], o2[3]};
}

// Ring slot of input row q is (q - r0 + 5) mod 11. Invariant at entry of step K
// (output row grow, (grow-r0)%11 == K): rings hold H-rows grow-6..grow+4, and
// pf = RAW x row grow+5 (prefetched last step). Step: issue prefetch of row
// grow+6, push pf through hrow into slot (K+10)%11 (evicting dead row grow-6),
// vertical 11-tap over both rings (pure registers, packed fp32), combine, store.
template<int K>
__device__ __forceinline__ void row_step(const float* __restrict__ xi,
                                         float* __restrict__ oi,
                                         f4 (&r1)[11], f4 (&r2)[11], f4& pf,
                                         int c, int grow,
                                         float mu1, float mu2,
                                         float md1, float md2) {
    f4 pn = load_row(xi, grow + 6, c);             // prefetch for step K+1

    constexpr int SN = (K + 10) % 11;
    hrow(pf, mu1, mu2, md1, md2, r1[SN], r2[SN]);  // rings: rows grow-5..grow+5

    // vertical 11-tap (symmetric pairs) on packed fp32, both streams
    constexpr int SC = (K + 5) % 11;
    f4 v1 = r1[SC] * GW5;
    f4 v2 = r2[SC] * GW5;
    #define VPAIR(D, G) { constexpr int A_ = (K + 5 - (D)) % 11;    \
                          constexpr int B_ = (K + 5 + (D)) % 11;    \
                          v1 = vfma(G, r1[A_] + r1[B_], v1);        \
                          v2 = vfma(G, r2[A_] + r2[B_], v2); }
    VPAIR(1, GW4) VPAIR(2, GW3) VPAIR(3, GW2) VPAIR(4, GW1) VPAIR(5, GW0)
    #undef VPAIR

    f4 o;
    o.x = sqrtf(fmaf(-v1.x, v1.x, v2.x) + 1e-6f);
    o.y = sqrtf(fmaf(-v1.y, v1.y, v2.y) + 1e-6f);
    o.z = sqrtf(fmaf(-v1.z, v1.z, v2.z) + 1e-6f);
    o.w = sqrtf(fmaf(-v1.w, v1.w, v2.w) + 1e-6f);
    *(f4*)(oi + (size_t)grow * W + c) = o;

    pf = pn;
}

__global__ __launch_bounds__(256, 4) void
local_std_kernel(const float* __restrict__ x, float* __restrict__ out) {
    const int t    = threadIdx.x;
    const int wv   = t >> 6;
    const int lane = t & 63;
    const int bid  = blockIdx.x;
    const int img  = bid >> 1;                  // 2 blocks per image
    const int half = bid & 1;
    const float* xi = x   + (size_t)img * IMG_PIX;
    float*       oi = out + (size_t)img * IMG_PIX;

    const int c  = lane << 2;                   // this lane's 4 columns
    const int r0 = half * (W / 2) + wv * BANDH; // band start (wave-private)

    // boundary masks for the shuffle halo (loop-invariant)
    const float mu1 = (lane >= 1)  ? 1.f : 0.f;
    const float mu2 = (lane >= 2)  ? 1.f : 0.f;
    const float md1 = (lane <= 62) ? 1.f : 0.f;
    const float md2 = (lane <= 61) ? 1.f : 0.f;

    // warm-up: H-rows r0-5..r0+4 into slots 0..9; slot 10 is filled at step 0.
    // Fully unrolled so all ring indices are compile-time (no scratch).
    f4 r1[11], r2[11];
    #pragma unroll
    for (int i = 0; i < 10; ++i) {
        f4 xr = load_row(xi, r0 - 5 + i, c);
        hrow(xr, mu1, mu2, md1, md2, r1[i], r2[i]);
    }
    r1[10] = (f4){0.f, 0.f, 0.f, 0.f};
    r2[10] = (f4){0.f, 0.f, 0.f, 0.f};
    f4 pf = load_row(xi, r0 + 5, c);            // raw row r0+5 for step 0

    // sweep 32 output rows; unroll-by-11 keeps ring/template indices static.
    // Outer loop kept rolled (uniform branches) to bound I-cache footprint.
    #pragma unroll 1
    for (int ii = 0; ii < 3; ++ii) {
        const int base = ii * 11;
        #define STEP(k) if (base + (k) < BANDH) \
            row_step<(k)>(xi, oi, r1, r2, pf, c, r0 + base + (k), mu1, mu2, md1, md2);
        STEP(0) STEP(1) STEP(2) STEP(3) STEP(4) STEP(5)
        STEP(6) STEP(7) STEP(8) STEP(9) STEP(10)
        #undef STEP
    }
}

extern "C" void kernel_launch(void* const* d_in, const int* in_sizes, int n_in,
                              void* d_out, int out_size, void* d_ws, size_t ws_size,
                              hipStream_t stream) {
    const float* x  = (const float*)d_in[0];
    float* out      = (float*)d_out;
    const int n_img = in_sizes[0] / IMG_PIX;    // 16*64 = 1024
    local_std_kernel<<<dim3(n_img * 2), 256, 0, stream>>>(x, out);
}

// Round 4
// 446.690 us; speedup vs baseline: 1.8607x; 1.8607x over previous
//
#include <hip/hip_runtime.h>
#include <math.h>

// LocalSTD: out = sqrt( G*x^2 - (G*x)^2 + 1e-6 ), G = 11x11 Gaussian (sigma=1),
// separable. x: [16,64,256,256] fp32 = 1024 images of 256x256.
//
// R7 = R5 + prefetch-by-2. R5 (vertical-first, single 11xf4 raw-x ring,
// shuffle halo exchange of v1/v2, no LDS) measured ~156us. Pipe budgets:
// HBM 100us, DS 49us, VALU 34us -> should be BW-bound at ~100us. The gap is
// in-flight bytes: prefetch-by-1 = 16KB/CU outstanding vs ~22KB
// bandwidth-delay product (24.6 GB/s/CU x ~900ns) -> ~72% of achievable BW,
// matching the measured 156us. Depth-2 prefetch (2 rows outstanding/wave,
// 32KB/CU) covers the BDP at the cost of +4 VGPRs -- safely under the
// (256,4) 128-VGPR cap that R4/R6 taught us never to exceed (spill = 3-5x).
//
// Wave = 64 lanes x 4 cols = full 256-col row. Vertical 11-tap from an 11-row
// float4 register ring. Horizontal 11-tap halo via 10 ds_bpermute per stream
// (__shfl_up/__shfl_down); boundary lanes zeroed by mask-multiply (image
// border is zero-padded; wave edges == image edges).

#define W        256
#define IMG_PIX  (W * W)
#define BANDH    32          // output rows per wave; block = 4 waves = 128 rows

// normalized 1D Gaussian sigma=1 (2D kernel = outer product, sums factorize)
#define GW0 1.4867195e-06f   // |d|=5
#define GW1 1.3383023e-04f   // |d|=4
#define GW2 4.4318485e-03f   // |d|=3
#define GW3 5.3990965e-02f   // |d|=2
#define GW4 2.4197072e-01f   // |d|=1
#define GW5 3.9894228e-01f   // center

typedef float f4 __attribute__((ext_vector_type(4)));

__device__ __forceinline__ f4 vfma(float g, f4 a, f4 c) {
    f4 gv = {g, g, g, g};
    return __builtin_elementwise_fma(gv, a, c);   // -> v_pk_fma_f32 pairs
}

__device__ __forceinline__ f4 load_row(const float* __restrict__ xi, int gr, int c) {
    if ((unsigned)gr < (unsigned)W)
        return *(const f4*)(xi + (size_t)gr * W + c);
    return (f4){0.f, 0.f, 0.f, 0.f};
}

__device__ __forceinline__ f4 shfl_up1(f4 v) {
    f4 r;
    r.x = __shfl_up(v.x, 1);
    r.y = __shfl_up(v.y, 1);
    r.z = __shfl_up(v.z, 1);
    r.w = __shfl_up(v.w, 1);
    return r;
}
__device__ __forceinline__ f4 shfl_dn1(f4 v) {
    f4 r;
    r.x = __shfl_down(v.x, 1);
    r.y = __shfl_down(v.y, 1);
    r.z = __shfl_down(v.z, 1);
    r.w = __shfl_down(v.w, 1);
    return r;
}

// Horizontal 11-tap for this lane's 4 cols of one stream. v = own float4
// (cols c..c+3). Halo via wave shuffles; boundary lanes (== image border)
// zeroed by mask-multiply (mu1: lane>=1, mu2: lane>=2, md1: lane<=62,
// md2: lane<=61). Shuffled garbage at the edge is the lane's own finite
// value, so *0.0f is safe.
__device__ __forceinline__ void hpass(f4 v, float mu1, float mu2,
                                      float md1, float md2, float h[4]) {
    f4 L = shfl_up1(v);                      // lane i-1: cols c-4..c-1
    float eL = __shfl_up(v.w, 2) * mu2;      // lane i-2 col c-5
    f4 R = shfl_dn1(v);                      // lane i+1: cols c+4..c+7
    float eR = __shfl_down(v.x, 2) * md2;    // lane i+2 col c+8
    L *= mu1;
    R *= md1;
    float F[14] = { eL,  L.x, L.y, L.z, L.w,
                    v.x, v.y, v.z, v.w,
                    R.x, R.y, R.z, R.w,  eR };   // F[k] = col c-5+k
    #pragma unroll
    for (int j = 0; j < 4; ++j) {
        float s = GW5 * F[j + 5];
        s = fmaf(GW4, F[j + 4] + F[j + 6],  s);
        s = fmaf(GW3, F[j + 3] + F[j + 7],  s);
        s = fmaf(GW2, F[j + 2] + F[j + 8],  s);
        s = fmaf(GW1, F[j + 1] + F[j + 9],  s);
        s = fmaf(GW0, F[j + 0] + F[j + 10], s);
        h[j] = s;
    }
}

// Ring slot of input row q is (q - r0 + 5) mod 11. Invariant at entry of step K
// (output row grow, (grow-r0)%11 == K): ring holds rows grow-6..grow+4;
// pf0 = row grow+5 (issued 2 steps ago, arrived), pf1 = row grow+6 (in
// flight). Step: insert pf0 (slot (K+10)%11, evicting dead row grow-6), issue
// prefetch of row grow+7, v-pass (packed fp32, squares recomputed -- saves 44
// VGPRs over a squares ring), h-pass, store, rotate prefetch regs.
template<int K>
__device__ __forceinline__ void row_step(const float* __restrict__ xi,
                                         float* __restrict__ oi,
                                         f4 (&xw)[11], f4& pf0, f4& pf1,
                                         int c, int grow,
                                         float mu1, float mu2,
                                         float md1, float md2) {
    constexpr int SN = (K + 10) % 11;
    xw[SN] = pf0;                                  // ring: rows grow-5..grow+5
    f4 pn = load_row(xi, grow + 7, c);             // arrives at step K+2

    // vertical 11-tap (symmetric pairs) on packed fp32
    constexpr int SC = (K + 5) % 11;
    f4 xc = xw[SC];
    f4 v1 = xc * GW5;
    f4 v2 = (xc * xc) * GW5;
    #define VPAIR(D, G) { constexpr int A_ = (K + 5 - (D)) % 11;                 \
                          constexpr int B_ = (K + 5 + (D)) % 11;                 \
                          f4 xa_ = xw[A_], xb_ = xw[B_];                         \
                          v1 = vfma(G, xa_ + xb_, v1);                           \
                          f4 sq_ = __builtin_elementwise_fma(xb_, xb_, xa_*xa_); \
                          v2 = vfma(G, sq_, v2); }
    VPAIR(1, GW4) VPAIR(2, GW3) VPAIR(3, GW2) VPAIR(4, GW1) VPAIR(5, GW0)
    #undef VPAIR

    // horizontal passes kept sequential (stream 1 then stream 2) to bound
    // live-range pressure.
    float h1[4], h2[4];
    hpass(v1, mu1, mu2, md1, md2, h1);
    hpass(v2, mu1, mu2, md1, md2, h2);

    f4 o;
    o.x = sqrtf(fmaf(-h1[0], h1[0], h2[0]) + 1e-6f);
    o.y = sqrtf(fmaf(-h1[1], h1[1], h2[1]) + 1e-6f);
    o.z = sqrtf(fmaf(-h1[2], h1[2], h2[2]) + 1e-6f);
    o.w = sqrtf(fmaf(-h1[3], h1[3], h2[3]) + 1e-6f);
    *(f4*)(oi + (size_t)grow * W + c) = o;

    pf0 = pf1;                                     // rotate prefetch pipeline
    pf1 = pn;
}

__global__ __launch_bounds__(256, 4) void
local_std_kernel(const float* __restrict__ x, float* __restrict__ out) {
    const int t    = threadIdx.x;
    const int wv   = t >> 6;
    const int lane = t & 63;
    const int bid  = blockIdx.x;
    const int img  = bid >> 1;                  // 2 blocks per image
    const int half = bid & 1;
    const float* xi = x   + (size_t)img * IMG_PIX;
    float*       oi = out + (size_t)img * IMG_PIX;

    const int c  = lane << 2;                   // this lane's 4 columns
    const int r0 = half * (W / 2) + wv * BANDH; // band start (wave-private)

    // boundary masks for the shuffle halo (loop-invariant)
    const float mu1 = (lane >= 1)  ? 1.f : 0.f;
    const float mu2 = (lane >= 2)  ? 1.f : 0.f;
    const float md1 = (lane <= 62) ? 1.f : 0.f;
    const float md2 = (lane <= 61) ? 1.f : 0.f;

    // warm-up: rows r0-5..r0+4 into slots 0..9; slot 10 is filled at step 0.
    f4 xw[11];
    #pragma unroll
    for (int i = 0; i < 10; ++i)
        xw[i] = load_row(xi, r0 - 5 + i, c);
    xw[10] = (f4){0.f, 0.f, 0.f, 0.f};
    f4 pf0 = load_row(xi, r0 + 5, c);           // for step 0 insert
    f4 pf1 = load_row(xi, r0 + 6, c);           // for step 1 insert

    // sweep 32 output rows; unroll-by-11 keeps ring/template indices static.
    // Outer loop kept rolled (uniform branches) to bound I-cache footprint.
    #pragma unroll 1
    for (int ii = 0; ii < 3; ++ii) {
        const int base = ii * 11;
        #define STEP(k) if (base + (k) < BANDH) \
            row_step<(k)>(xi, oi, xw, pf0, pf1, c, r0 + base + (k), mu1, mu2, md1, md2);
        STEP(0) STEP(1) STEP(2) STEP(3) STEP(4) STEP(5)
        STEP(6) STEP(7) STEP(8) STEP(9) STEP(10)
        #undef STEP
    }
}

extern "C" void kernel_launch(void* const* d_in, const int* in_sizes, int n_in,
                              void* d_out, int out_size, void* d_ws, size_t ws_size,
                              hipStream_t stream) {
    const float* x  = (const float*)d_in[0];
    float* out      = (float*)d_out;
    const int n_img = in_sizes[0] / IMG_PIX;    // 16*64 = 1024
    local_std_kernel<<<dim3(n_img * 2), 256, 0, stream>>>(x, out);
}